// Round 3
// baseline (446.774 us; speedup 1.0000x reference)
//
#include <hip/hip_runtime.h>
#include <math.h>

#define HIDDEN 256
#define NUM_CLASSES 53
#define CHUNK 64          // rows per K1 block
#define CAP 66            // max local bags tracked per K1 block

// ---------------- K0: seg fill + zero bag sums ----------------
__global__ __launch_bounds__(256) void k0_seg(
    const int* __restrict__ scope, int* __restrict__ seg,
    float* __restrict__ s, int n_bags)
{
    const int gtid = blockIdx.x * blockDim.x + threadIdx.x;
    if (gtid < 2 * n_bags) s[gtid] = 0.f;
    const int wid  = gtid >> 6;      // one wave per bag
    const int lane = gtid & 63;
    if (wid < n_bags) {
        const int st = scope[wid], en = scope[wid + 1];
        for (int i = st + lane; i < en; i += 64) seg[i] = wid;
    }
}

// ---------------- K1: logits -> e, bag sums (balanced) ----------------
__global__ __launch_bounds__(256) void k1_logits(
    const float* __restrict__ x,
    const float* __restrict__ rel_emb0,
    const float* __restrict__ rel_emb1,
    const int* __restrict__ relation_levels,
    const int* __restrict__ label_index,
    const int* __restrict__ seg,
    float* __restrict__ e,
    float* __restrict__ s)
{
    const int c0   = blockIdx.x * CHUNK;
    const int tid  = threadIdx.x;
    const int lane = tid & 63;
    const int wave = tid >> 6;
    const int half = lane >> 5;
    const int j    = lane & 31;
    const int colb = j * 8;
    const int stream = wave * 2 + half;   // 0..7

    __shared__ float s_local[2 * CAP];
    __shared__ int   s_seg0;
    if (tid == 0) s_seg0 = seg[c0];
    for (int t = tid; t < 2 * CAP; t += 256) s_local[t] = 0.f;
    __syncthreads();
    const int seg0 = s_seg0;

    #pragma unroll
    for (int k = 0; k < CHUNK / 8; ++k) {
        const int row = c0 + 8 * k + stream;   // 8 streams read 8 contiguous rows
        const float* xp = x + (size_t)row * HIDDEN + colb;
        const float4 xa = *reinterpret_cast<const float4*>(xp);
        const float4 xb = *reinterpret_cast<const float4*>(xp + 4);
        const int lbl = label_index[row];                       // uniform per half
        const int2 rl = *reinterpret_cast<const int2*>(relation_levels + 2 * lbl);
        const float* p0 = rel_emb0 + (size_t)rl.x * HIDDEN + colb;
        const float* p1 = rel_emb1 + (size_t)rl.y * HIDDEN + colb;
        const float4 r0a = *reinterpret_cast<const float4*>(p0);
        const float4 r0b = *reinterpret_cast<const float4*>(p0 + 4);
        const float4 r1a = *reinterpret_cast<const float4*>(p1);
        const float4 r1b = *reinterpret_cast<const float4*>(p1 + 4);

        float lg0 = xa.x*r0a.x + xa.y*r0a.y + xa.z*r0a.z + xa.w*r0a.w
                  + xb.x*r0b.x + xb.y*r0b.y + xb.z*r0b.z + xb.w*r0b.w;
        float lg1 = xa.x*r1a.x + xa.y*r1a.y + xa.z*r1a.z + xa.w*r1a.w
                  + xb.x*r1b.x + xb.y*r1b.y + xb.z*r1b.z + xb.w*r1b.w;

        #pragma unroll
        for (int off = 16; off > 0; off >>= 1) {   // 32-lane reduce, stays in half
            lg0 += __shfl_xor(lg0, off, 64);
            lg1 += __shfl_xor(lg1, off, 64);
        }

        if (j == 0) {
            const float e0 = __expf(lg0);
            const float e1 = __expf(lg1);
            e[2 * row]     = e0;
            e[2 * row + 1] = e1;
            const int sg = seg[row];
            const int lb = sg - seg0;
            if (lb < CAP) {
                atomicAdd(&s_local[2 * lb],     e0);
                atomicAdd(&s_local[2 * lb + 1], e1);
            } else {
                atomicAdd(&s[2 * sg],     e0);
                atomicAdd(&s[2 * sg + 1], e1);
            }
        }
    }
    __syncthreads();
    for (int t = tid; t < 2 * CAP; t += 256) {
        const float v = s_local[t];
        if (v != 0.f) atomicAdd(&s[2 * seg0 + t], v);
    }
}

// ---------------- K2: weighted bag reduction + head ----------------
__global__ __launch_bounds__(256) void k2_weighted(
    const float* __restrict__ x,
    const float* __restrict__ e,
    const float* __restrict__ s,
    const float* __restrict__ disc,
    const float* __restrict__ bias,
    const int* __restrict__ scope,
    float* __restrict__ out)
{
    const int bag   = blockIdx.x;
    const int start = scope[bag];
    const int end   = scope[bag + 1];

    const int tid  = threadIdx.x;
    const int lane = tid & 63;
    const int wave = tid >> 6;
    const int half = lane >> 5;
    const int j    = lane & 31;
    const int colb = j * 8;
    const int stream = wave * 2 + half;   // 0..7 row streams

    const float sv0 = s[2 * bag], sv1 = s[2 * bag + 1];
    const float i0 = (end > start) ? 1.f / sv0 : 0.f;
    const float i1 = (end > start) ? 1.f / sv1 : 0.f;

    float4 a0 = make_float4(0,0,0,0), b0 = make_float4(0,0,0,0);
    float4 a1 = make_float4(0,0,0,0), b1 = make_float4(0,0,0,0);

    for (int r = start + stream; r < end; r += 16) {
        const int r2  = r + 8;
        const bool v2 = (r2 < end);
        const int r2c = v2 ? r2 : r;

        const float2 ew1 = *reinterpret_cast<const float2*>(e + 2 * r);
        const float2 ew2 = *reinterpret_cast<const float2*>(e + 2 * r2c);
        const float* xp1 = x + (size_t)r   * HIDDEN + colb;
        const float* xp2 = x + (size_t)r2c * HIDDEN + colb;
        const float4 x1a = *reinterpret_cast<const float4*>(xp1);
        const float4 x1b = *reinterpret_cast<const float4*>(xp1 + 4);
        const float4 x2a = *reinterpret_cast<const float4*>(xp2);
        const float4 x2b = *reinterpret_cast<const float4*>(xp2 + 4);

        const float w10 = ew1.x * i0, w11 = ew1.y * i1;
        const float w20 = v2 ? ew2.x * i0 : 0.f;
        const float w21 = v2 ? ew2.y * i1 : 0.f;

        a0.x += w10*x1a.x + w20*x2a.x;  a0.y += w10*x1a.y + w20*x2a.y;
        a0.z += w10*x1a.z + w20*x2a.z;  a0.w += w10*x1a.w + w20*x2a.w;
        b0.x += w10*x1b.x + w20*x2b.x;  b0.y += w10*x1b.y + w20*x2b.y;
        b0.z += w10*x1b.z + w20*x2b.z;  b0.w += w10*x1b.w + w20*x2b.w;
        a1.x += w11*x1a.x + w21*x2a.x;  a1.y += w11*x1a.y + w21*x2a.y;
        a1.z += w11*x1a.z + w21*x2a.z;  a1.w += w11*x1a.w + w21*x2a.w;
        b1.x += w11*x1b.x + w21*x2b.x;  b1.y += w11*x1b.y + w21*x2b.y;
        b1.z += w11*x1b.z + w21*x2b.z;  b1.w += w11*x1b.w + w21*x2b.w;
    }

    // ---- merge 8 streams via LDS ----
    __shared__ float s_o[2][8][HIDDEN];     // 16 KB
    __shared__ float s_repre[2 * HIDDEN];   // 2 KB
    {
        float4* d0 = reinterpret_cast<float4*>(&s_o[0][stream][colb]);
        d0[0] = a0; d0[1] = b0;
        float4* d1 = reinterpret_cast<float4*>(&s_o[1][stream][colb]);
        d1[0] = a1; d1[1] = b1;
    }
    __syncthreads();
    {
        const int t = tid;   // hidden column
        #pragma unroll
        for (int h = 0; h < 2; ++h) {
            float acc = 0.f;
            #pragma unroll
            for (int w = 0; w < 8; ++w) acc += s_o[h][w][t];
            s_repre[h * HIDDEN + t] = acc;
        }
    }
    __syncthreads();

    // ---- head: out[bag][c] = <repre(512), disc[c]> + bias[c] ----
    for (int c = wave; c < NUM_CLASSES; c += 4) {
        const float* dr = disc + c * (2 * HIDDEN);
        float p = 0.f;
        #pragma unroll
        for (int k = 0; k < 8; ++k) {
            const int idx = lane + k * 64;
            p += s_repre[idx] * dr[idx];
        }
        #pragma unroll
        for (int off = 32; off > 0; off >>= 1)
            p += __shfl_xor(p, off, 64);
        if (lane == 0)
            out[bag * NUM_CLASSES + c] = p + bias[c];
    }
}

extern "C" void kernel_launch(void* const* d_in, const int* in_sizes, int n_in,
                              void* d_out, int out_size, void* d_ws, size_t ws_size,
                              hipStream_t stream) {
    const float* x               = (const float*)d_in[0];
    const float* rel_emb0        = (const float*)d_in[1];
    const float* rel_emb1        = (const float*)d_in[2];
    const float* disc            = (const float*)d_in[3];
    const float* bias            = (const float*)d_in[4];
    const int*   relation_levels = (const int*)d_in[5];
    const int*   label_index     = (const int*)d_in[6];
    const int*   scope           = (const int*)d_in[7];
    float*       out             = (float*)d_out;

    const int n_bags = in_sizes[7] - 1;      // 4096
    const int n_rows = in_sizes[6];          // 262144

    // workspace layout: s[2*n_bags] f32 | e[2*n_rows] f32 | seg[n_rows] i32
    float* s_ws  = (float*)d_ws;
    float* e_ws  = s_ws + 2 * n_bags;
    int*   seg   = (int*)(e_ws + 2 * (size_t)n_rows);

    // K0: one wave per bag
    {
        const int waves  = n_bags;
        const int blocks = (waves * 64 + 255) / 256;
        k0_seg<<<blocks, 256, 0, stream>>>(scope, seg, s_ws, n_bags);
    }
    // K1: 64 contiguous rows per block
    k1_logits<<<n_rows / CHUNK, 256, 0, stream>>>(
        x, rel_emb0, rel_emb1, relation_levels, label_index, seg, e_ws, s_ws);
    // K2: one block per bag
    k2_weighted<<<n_bags, 256, 0, stream>>>(
        x, e_ws, s_ws, disc, bias, scope, out);
}